// Round 9
// baseline (447.050 us; speedup 1.0000x reference)
//
#include <hip/hip_runtime.h>
#include <hip/hip_bf16.h>
#include <hip/hip_fp16.h>

#define NB 8192
#define D_IN 3200
#define D_H 128
#define NE 5

typedef _Float16 f16x8 __attribute__((ext_vector_type(8)));
typedef _Float16 f16x4 __attribute__((ext_vector_type(4)));
typedef float f32x4 __attribute__((ext_vector_type(4)));

// async global->LDS, 16B per lane; global addr may be per-lane, LDS base wave-uniform
__device__ __forceinline__ void gload16(const _Float16* g, _Float16* l) {
    __builtin_amdgcn_global_load_lds(
        (const __attribute__((address_space(1))) void*)g,
        (__attribute__((address_space(3))) void*)l, 16, 0, 0);
}

__device__ __forceinline__ unsigned pack_hl(float v) {
    _Float16 vh = (_Float16)v;
    _Float16 vl = (_Float16)(v - (float)vh);
    unsigned short uh, ul;
    __builtin_memcpy(&uh, &vh, 2);
    __builtin_memcpy(&ul, &vl, 2);
    return (unsigned)uh | ((unsigned)ul << 16);
}

// ---------------- kernel 0: prep — ROUND-4 EXACT (frozen)
// wpk: [0,5120) b2h | [5120,10240) b2l | [10240,10880) b1h | [10880,11520) b1l
__global__ __launch_bounds__(256) void k_prep(const float* __restrict__ gw,
                                              const float* __restrict__ c2w,
                                              const float* __restrict__ c1w,
                                              float* __restrict__ gwC,
                                              _Float16* __restrict__ wpk,
                                              int* __restrict__ cnt) {
    int i = blockIdx.x * 256 + threadIdx.x;
    if (i < 16000) {
        int e = i / 3200, rem = i - e * 3200;
        int o = rem >> 5, co = rem & 31;
        gwC[i] = gw[(co * 100 + o) * 5 + e];
    } else if (i < 21120) {
        int j = i - 16000;                 // b2 pack, j in [0,5120)
        int co = j / 160, k = j - co * 160;
        int s = k >> 4, ci = k & 15;
        float v = (s == 9) ? 0.f : c2w[(co * 16 + ci) * 9 + s];
        _Float16 vh = (_Float16)v;
        wpk[j] = vh;
        wpk[5120 + j] = (_Float16)(v - (float)vh);
    } else if (i < 21760) {
        int j = i - 21120;                 // b1 pack, j in [0,640) = [c][k<40]
        int c = (j * 1639) >> 16;          // j/40
        int k = j - c * 40;
        float v = (k < 25) ? c1w[c * 25 + k] : 0.f;
        _Float16 vh = (_Float16)v;
        wpk[10240 + j] = vh;
        wpk[10880 + j] = (_Float16)(v - (float)vh);
    }
    if (blockIdx.x == 0 && threadIdx.x < NE) cnt[threadIdx.x] = 0;
}

// ---------------- kernel 1: blocks 0-519 = wT/e2T transpose prep; blocks 520+ = conv path.
// ROUND-4 EXACT structure + round-9: compaction fused into the t==0 tail (3 atomics
// per token, ~4.9k per counter spread over ~107us: absorbed; removes k_compact launch).
#define PCL_S 24
__global__ __launch_bounds__(256, 4) void k_feat(
    const float* __restrict__ x, const float* __restrict__ c1b,
    const float* __restrict__ c2b,
    const float* __restrict__ gwC, const float* __restrict__ gb,
    const _Float16* __restrict__ wpk,
    const float* __restrict__ e1w, _Float16* __restrict__ wT,
    const float* __restrict__ e2w, _Float16* __restrict__ e2T,
    _Float16* __restrict__ h16, float* __restrict__ wfull,
    int* __restrict__ cnt, int* __restrict__ lists)
{
    __shared__ union {
        struct {
            __align__(16) _Float16 b2h[5120];   // contiguous staging run start
            __align__(16) _Float16 b2l[5120];
            __align__(16) _Float16 b1h[640];
            __align__(16) _Float16 b1l[640];
            __align__(16) unsigned xs_hl[784];
            __align__(16) _Float16 pclh[144 * PCL_S];
            __align__(16) _Float16 pcll[144 * PCL_S];
            float red[32];
        } f;
        float tile[64 * 65];   // prep transpose scratch (16.6 KB, overlaid)
    } S;
    int bid = blockIdx.x;
    int t = threadIdx.x;

    if (bid < 520) {               // ---- prep path
        if (bid < 500) {           // e1_w [5][3200][128] -> f16 T [5][128][3200]
            int e = bid / 100, rem = bid - e * 100;
            int k0 = (rem >> 1) * 64, n0 = (rem & 1) * 64;
            const float* src = e1w + (size_t)e * D_IN * D_H;
            _Float16* dst = wT + (size_t)e * D_H * D_IN;
            for (int i = 0; i < 16; ++i) {
                int idx = t + i * 256;
                int kr = idx >> 6, nc = idx & 63;
                S.tile[kr * 65 + nc] = src[(size_t)(k0 + kr) * D_H + n0 + nc];
            }
            __syncthreads();
            for (int i = 0; i < 16; ++i) {
                int idx = t + i * 256;
                int nr = idx >> 6, kc = idx & 63;
                dst[(size_t)(n0 + nr) * D_IN + k0 + kc] = (_Float16)S.tile[kc * 65 + nr];
            }
        } else {                   // e2_w [5][128][128] -> f16 T (n,k)
            int idx2 = bid - 500;
            int e = idx2 >> 2, rem = idx2 & 3;
            int k0 = (rem >> 1) * 64, n0 = (rem & 1) * 64;
            const float* src = e2w + (size_t)e * D_H * D_H;
            _Float16* dst = e2T + (size_t)e * D_H * D_H;
            for (int i = 0; i < 16; ++i) {
                int idx = t + i * 256;
                int kr = idx >> 6, nc = idx & 63;
                S.tile[kr * 65 + nc] = src[(size_t)(k0 + kr) * D_H + n0 + nc];
            }
            __syncthreads();
            for (int i = 0; i < 16; ++i) {
                int idx = t + i * 256;
                int nr = idx >> 6, kc = idx & 63;
                dst[(size_t)(n0 + nr) * D_H + k0 + kc] = (_Float16)S.tile[kc * 65 + nr];
            }
        }
        return;
    }

    int b = bid - 520;             // ---- conv path
    int lane = t & 63, wv = t >> 6;
    int quad = lane >> 4, l16 = lane & 15;

    // weight staging: 23040 B = 1440 x 16B chunks, async DMA, no VALU repack
    {
        _Float16* ldst = S.f.b2h;
        #pragma unroll
        for (int it = 0; it < 6; ++it) {
            int ci = t + it * 256;
            if (ci < 1440)
                gload16(wpk + ci * 8, ldst + (it * 256 + wv * 64) * 8);
        }
    }
    // x -> packed hi/lo f16 words
    for (int i = t; i < 784; i += 256)
        S.f.xs_hl[i] = pack_hl(x[(size_t)b * 784 + i]);
    __syncthreads();

    // ---- conv1 MFMA + fused 2x2 maxpool
    {
        f16x8 b1hf = *(const f16x8*)&S.f.b1h[l16 * 40 + quad * 8];
        f16x8 b1lf = *(const f16x8*)&S.f.b1l[l16 * 40 + quad * 8];
        float bias1 = c1b[l16];
        int offw[8];
        #pragma unroll
        for (int j = 0; j < 8; ++j) {
            int k = quad * 8 + j; if (k > 24) k = 24;     // B is zero for k>=25
            int uu = (k * 205) >> 10;                     // k/5
            offw[j] = k + 23 * uu;                        // u*28+v
        }
        int s_ = l16 & 3, qof = l16 >> 2;
        int dy = s_ >> 1, dx = s_ & 1;
        for (int T = wv * 9; T < wv * 9 + 9; ++T) {
            int q = T * 4 + qof;                          // A row's pooled pixel
            int qy = (q * 683) >> 13, qx = q - qy * 12;   // q/12, q%12
            int base = (2 * qy + dy) * 28 + 2 * qx + dx;
            unsigned w[8];
            #pragma unroll
            for (int j = 0; j < 8; ++j) w[j] = S.f.xs_hl[base + offw[j]];
            union { f16x8 v; unsigned u[4]; } ah, al;
            #pragma unroll
            for (int jj = 0; jj < 4; ++jj) {
                ah.u[jj] = __builtin_amdgcn_perm(w[2 * jj + 1], w[2 * jj], 0x05040100u);
                al.u[jj] = __builtin_amdgcn_perm(w[2 * jj + 1], w[2 * jj], 0x07060302u);
            }
            f32x4 a1 = (f32x4){0.f, 0.f, 0.f, 0.f};
            a1 = __builtin_amdgcn_mfma_f32_16x16x32_f16(ah.v, b1hf, a1, 0, 0, 0);
            a1 = __builtin_amdgcn_mfma_f32_16x16x32_f16(ah.v, b1lf, a1, 0, 0, 0);
            a1 = __builtin_amdgcn_mfma_f32_16x16x32_f16(al.v, b1hf, a1, 0, 0, 0);
            // lane holds the 4 pool sources of pooled pixel pos = T*4+quad, channel l16
            float pv = fmaxf(fmaxf(a1[0], a1[1]), fmaxf(a1[2], a1[3]));
            pv = fmaxf(pv + bias1, 0.f);
            int pos = T * 4 + quad;
            _Float16 vh = (_Float16)pv;
            S.f.pclh[pos * PCL_S + l16] = vh;
            S.f.pcll[pos * PCL_S + l16] = (_Float16)(pv - (float)vh);
        }
    }
    __syncthreads();

    // conv2 MFMA: wave fixed nt (B frags in regs), mt strided  (proven structure, frozen)
    float part[5] = {0, 0, 0, 0, 0};
    int quadh = quad >> 1, quadl = quad & 1;
    const int offA[5] = {0, 2, 13, 24, 26};
    const int offB[5] = {1, 12, 14, 25, 0};
    {
        int nt = wv & 1;
        int co = nt * 16 + l16;
        f16x8 bh[5], bl[5];
        #pragma unroll
        for (int kc = 0; kc < 5; ++kc) {
            bh[kc] = *(const f16x8*)&S.f.b2h[co * 160 + kc * 32 + quad * 8];
            bl[kc] = *(const f16x8*)&S.f.b2l[co * 160 + kc * 32 + quad * 8];
        }
        float bco = c2b[co];
        for (int mt = wv >> 1; mt < 7; mt += 2) {
            int o_a = mt * 16 + l16;
            int o_cl = o_a < 100 ? o_a : 99;
            int pb = (o_cl / 10) * 12 + (o_cl % 10);
            f32x4 acc = (f32x4){0.f, 0.f, 0.f, 0.f};
            #pragma unroll
            for (int kc = 0; kc < 5; ++kc) {
                int off = quadh ? offB[kc] : offA[kc];
                f16x8 ah = *(const f16x8*)&S.f.pclh[(pb + off) * PCL_S + quadl * 8];
                f16x8 al = *(const f16x8*)&S.f.pcll[(pb + off) * PCL_S + quadl * 8];
                acc = __builtin_amdgcn_mfma_f32_16x16x32_f16(ah, bh[kc], acc, 0, 0, 0);
                acc = __builtin_amdgcn_mfma_f32_16x16x32_f16(ah, bl[kc], acc, 0, 0, 0);
                acc = __builtin_amdgcn_mfma_f32_16x16x32_f16(al, bh[kc], acc, 0, 0, 0);
            }
            if (mt < 6 || quad == 0) {
                int o0 = mt * 16 + quad * 4;
                f16x4 st;
                #pragma unroll
                for (int r = 0; r < 4; ++r) {
                    float hv = fmaxf(acc[r] + bco, 0.f);
                    st[r] = (_Float16)hv;
                    #pragma unroll
                    for (int e = 0; e < 5; ++e)
                        part[e] += hv * gwC[e * 3200 + (o0 + r) * 32 + co];
                }
                *(f16x4*)&h16[(size_t)b * D_IN + co * 100 + o0] = st;
            }
        }
    }

    // gate reduce: softmax, top-3 renormalized; fused list insertion (round-9)
    #pragma unroll
    for (int e = 0; e < 5; ++e) {
        float v = part[e];
        for (int off = 32; off > 0; off >>= 1) v += __shfl_down(v, off, 64);
        if (lane == 0) S.f.red[wv * 8 + e] = v;
    }
    __syncthreads();
    if (t == 0) {
        float lg[5], p[5];
        float mx = -1e30f;
        for (int e = 0; e < 5; ++e) {
            lg[e] = S.f.red[e] + S.f.red[8 + e] + S.f.red[16 + e] + S.f.red[24 + e] + gb[e];
            mx = fmaxf(mx, lg[e]);
        }
        float sum = 0.f;
        for (int e = 0; e < 5; ++e) { p[e] = expf(lg[e] - mx); sum += p[e]; }
        for (int e = 0; e < 5; ++e) p[e] /= sum;
        bool used[5] = {false, false, false, false, false};
        float out5[5] = {0, 0, 0, 0, 0};
        int ti[3]; float tv[3]; float tsum = 0.f;
        for (int jj = 0; jj < 3; ++jj) {
            int best = 0; float bv = -1.f;
            for (int e = 0; e < 5; ++e)
                if (!used[e] && p[e] > bv) { bv = p[e]; best = e; }
            used[best] = true; ti[jj] = best; tv[jj] = bv; tsum += bv;
        }
        for (int jj = 0; jj < 3; ++jj) out5[ti[jj]] = tv[jj] / tsum;
        for (int e = 0; e < 5; ++e) wfull[b * 5 + e] = out5[e];
        #pragma unroll
        for (int jj = 0; jj < 3; ++jj) {
            int pos = atomicAdd(&cnt[ti[jj]], 1);
            lists[ti[jj] * NB + pos] = b;
        }
    }
}

// ---------------- kernel 2: experts on compacted lists, 64-row M-tiles — ROUND-7 EXACT
// (measured best). 3-deep staging ring, steady-state vmcnt(12) (2 stages in flight,
// never drained). Phase-2 B frags read e2T DIRECT from global (L2-hot per expert).
// h1s/smwT overlay dead staging. 74KB -> 2 blocks/CU.
#define H1S 136
union __align__(16) SLds {
    struct { _Float16 d[12288]; } p[3];               // 3 x 24KB staging
    struct {
        __align__(16) _Float16 h1s[64 * H1S];         // 17.4 KB activations (phase 2/3)
        __align__(16) _Float16 smwT[2048];            // 4 KB head weights^T (phase 3)
    } q;
};

__global__ __launch_bounds__(256, 2) void k_e1e2(
    const _Float16* __restrict__ h16, const _Float16* __restrict__ wT,
    const _Float16* __restrict__ e2T,
    const float* __restrict__ e1b, const float* __restrict__ e2b,
    const float* __restrict__ smw,
    const float* __restrict__ wfull, const int* __restrict__ cnt,
    const int* __restrict__ lists, float* __restrict__ logits)
{
    __shared__ SLds u;
    __shared__ float wfl[64];
    __shared__ int rows[64];
    int bid = blockIdx.x;
    int e = bid >> 7;            // expert-major: one B matrix hot per L2 at a time
    int mt = bid & 127;
    int cnt_e = cnt[e];
    int m0 = mt * 64;
    if (m0 >= cnt_e) return;     // inactive tile, uniform exit
    int t = threadIdx.x;
    int lane = t & 63, wv = t >> 6;
    int waveM = wv >> 1, waveN = wv & 1;
    int quad = lane >> 4, l16 = lane & 15;
    if (t < 64) {
        int r = m0 + t;
        int row = (r < cnt_e) ? lists[e * NB + r] : lists[e * NB];  // dup row for tail
        rows[t] = row;
        wfl[t] = (r < cnt_e) ? wfull[(size_t)row * 5 + e] : 0.f;    // tail w=0
    }
    __syncthreads();

    const _Float16* bbase = wT + (size_t)e * (D_H * D_IN);
    int srow = t >> 2;
    int scol = (t & 3) * 8;
    const _Float16* aptr = h16 + (size_t)rows[srow] * D_IN + scol;
    const _Float16* bptr0 = bbase + (size_t)srow * D_IN + scol;
    const _Float16* bptr1 = bbase + (size_t)(64 + srow) * D_IN + scol;
    f32x4 acc[2][4];
    #pragma unroll
    for (int i = 0; i < 2; ++i)
        #pragma unroll
        for (int j = 0; j < 4; ++j) acc[i][j] = (f32x4){0.f, 0.f, 0.f, 0.f};

    _Float16* bcur = (_Float16*)&u.p[0];
    _Float16* bnxt = (_Float16*)&u.p[1];
    _Float16* bnx2 = (_Float16*)&u.p[2];
    // buffer layout: [0]=As0(k lo half), [2048]=As1(k hi), [4096]=Bs0, [8192]=Bs1
    #define STAGE(base, kk)                                           \
        do {                                                          \
            gload16(aptr  + (kk),        (base) + 0    + wv * 512);   \
            gload16(aptr  + (kk) + 32,   (base) + 2048 + wv * 512);   \
            gload16(bptr0 + (kk),        (base) + 4096 + wv * 512);   \
            gload16(bptr0 + (kk) + 32,   (base) + 8192 + wv * 512);   \
            gload16(bptr1 + (kk),        (base) + 4096 + 2048 + wv * 512); \
            gload16(bptr1 + (kk) + 32,   (base) + 8192 + 2048 + wv * 512); \
        } while (0)

    STAGE(bcur, 0);                               // prologue: steps 0,1 in flight
    STAGE(bnxt, 64);
    const int NT = D_IN / 64;                     // 50
    for (int it = 0; it < NT; ++it) {
        if (it + 2 < NT) {
            STAGE(bnx2, (it + 2) * 64);           // keep 2 stages in flight
            asm volatile("s_waitcnt vmcnt(12)" ::: "memory");  // oldest stage (it) done
        } else if (it + 1 < NT) {
            asm volatile("s_waitcnt vmcnt(6)" ::: "memory");
        } else {
            asm volatile("s_waitcnt vmcnt(0)" ::: "memory");
        }
        __builtin_amdgcn_s_barrier();             // all waves: bcur fully populated
        __builtin_amdgcn_sched_barrier(0);
        #pragma unroll
        for (int ch = 0; ch < 2; ++ch) {
            const _Float16* Ab = bcur + (ch ? 2048 : 0);
            const _Float16* Bb = bcur + 4096 + (ch ? 4096 : 0);
            f16x8 af[2], bf[4];
            #pragma unroll
            for (int ms = 0; ms < 2; ++ms)
                af[ms] = *(const f16x8*)&Ab[(waveM * 32 + ms * 16 + l16) * 32 + quad * 8];
            #pragma unroll
            for (int ns = 0; ns < 4; ++ns)
                bf[ns] = *(const f16x8*)&Bb[(waveN * 64 + ns * 16 + l16) * 32 + quad * 8];
            #pragma unroll
            for (int ms = 0; ms < 2; ++ms)
                #pragma unroll
                for (int ns = 0; ns < 4; ++ns)
                    acc[ms][ns] = __builtin_amdgcn_mfma_f32_16x16x32_f16(af[ms], bf[ns], acc[ms][ns], 0, 0, 0);
        }
        __builtin_amdgcn_s_barrier();             // all reads retired -> bcur reusable
        _Float16* t0 = bcur; bcur = bnxt; bnxt = bnx2; bnx2 = t0;
    }
    #undef STAGE

    // h1 = tanh(acc + b1) -> h1s (staging dead; q overlays p)
    #pragma unroll
    for (int ms = 0; ms < 2; ++ms) {
        int rbase = waveM * 32 + ms * 16 + quad * 4;
        #pragma unroll
        for (int ns = 0; ns < 4; ++ns) {
            int n = waveN * 64 + ns * 16 + l16;
            float bias = e1b[e * D_H + n];
            #pragma unroll
            for (int r = 0; r < 4; ++r)
                u.q.h1s[(rbase + r) * H1S + n] = (_Float16)tanhf(acc[ms][ns][r] + bias);
        }
    }
    __syncthreads();   // h1s visible

    // phase 2: h1 @ e2^T, B frags direct from global e2T (L2-hot, shared per expert)
    const _Float16* e2g = e2T + (size_t)e * (D_H * D_H);
    f32x4 acc2[2][4];
    #pragma unroll
    for (int i = 0; i < 2; ++i)
        #pragma unroll
        for (int j = 0; j < 4; ++j) acc2[i][j] = (f32x4){0.f, 0.f, 0.f, 0.f};
    #pragma unroll
    for (int kc = 0; kc < 4; ++kc) {
        f16x8 a2[2], b2[4];
        #pragma unroll
        for (int ms = 0; ms < 2; ++ms)
            a2[ms] = *(const f16x8*)&u.q.h1s[(waveM * 32 + ms * 16 + l16) * H1S + kc * 32 + quad * 8];
        #pragma unroll
        for (int ns = 0; ns < 4; ++ns)
            b2[ns] = *(const f16x8*)&e2g[(size_t)(waveN * 64 + ns * 16 + l16) * D_H + kc * 32 + quad * 8];
        #pragma unroll
        for (int ms = 0; ms < 2; ++ms)
            #pragma unroll
            for (int ns = 0; ns < 4; ++ns)
                acc2[ms][ns] = __builtin_amdgcn_mfma_f32_16x16x32_f16(a2[ms], b2[ns], acc2[ms][ns], 0, 0, 0);
    }
    __syncthreads();   // all h1s reads done -> safe to overwrite with wh2

    // stage smw^T [16(n, zero-padded)][128(k)] f16; wh2 = w*tanh(acc2+b2) -> h1s
    _Float16* smwT = u.q.smwT;
    for (int i = t; i < 2048; i += 256) {
        int n = i >> 7, k = i & 127;
        smwT[i] = (_Float16)(n < 10 ? smw[k * 10 + n] : 0.f);
    }
    #pragma unroll
    for (int ms = 0; ms < 2; ++ms) {
        int rbase = waveM * 32 + ms * 16 + quad * 4;
        #pragma unroll
        for (int ns = 0; ns < 4; ++ns) {
            int n = waveN * 64 + ns * 16 + l16;
            float bias = e2b[e * D_H + n];
            #pragma unroll
            for (int r = 0; r < 4; ++r) {
                int lrow = rbase + r;
                u.q.h1s[lrow * H1S + n] = (_Float16)(wfl[lrow] * tanhf(acc2[ms][ns][r] + bias));
            }
        }
    }
    __syncthreads();

    // MFMA head: per wave one 16-row m-tile: wh2[16x128] @ smw^T[16x128] -> atomic logits
    {
        f32x4 acc3 = (f32x4){0.f, 0.f, 0.f, 0.f};
        #pragma unroll
        for (int kc = 0; kc < 4; ++kc) {
            f16x8 a3 = *(const f16x8*)&u.q.h1s[(wv * 16 + l16) * H1S + kc * 32 + quad * 8];
            f16x8 b3 = *(const f16x8*)&smwT[l16 * 128 + kc * 32 + quad * 8];
            acc3 = __builtin_amdgcn_mfma_f32_16x16x32_f16(a3, b3, acc3, 0, 0, 0);
        }
        if (l16 < 10) {     // D: row = quad*4+r, col = l16
            #pragma unroll
            for (int r = 0; r < 4; ++r) {
                int row = wv * 16 + quad * 4 + r;
                unsafeAtomicAdd(&logits[(size_t)rows[row] * 10 + l16], acc3[r]);
            }
        }
    }
}

// ---------------- kernel 3: softmax over logits (+smb) -> out
__global__ __launch_bounds__(256) void k_smax(
    const float* __restrict__ logits, const float* __restrict__ smb,
    float* __restrict__ out)
{
    int r = blockIdx.x * 256 + threadIdx.x;
    float lg[10];
    float mx = -1e30f;
    #pragma unroll
    for (int c = 0; c < 10; ++c) {
        lg[c] = logits[(size_t)r * 10 + c] + smb[c];
        mx = fmaxf(mx, lg[c]);
    }
    float s = 0.f;
    #pragma unroll
    for (int c = 0; c < 10; ++c) { lg[c] = expf(lg[c] - mx); s += lg[c]; }
    float inv = 1.f / s;
    #pragma unroll
    for (int c = 0; c < 10; ++c) out[(size_t)r * 10 + c] = lg[c] * inv;
}

extern "C" void kernel_launch(void* const* d_in, const int* in_sizes, int n_in,
                              void* d_out, int out_size, void* d_ws, size_t ws_size,
                              hipStream_t stream)
{
    const float* x   = (const float*)d_in[0];
    const float* c1w = (const float*)d_in[1];
    const float* c1b = (const float*)d_in[2];
    const float* c2w = (const float*)d_in[3];
    const float* c2b = (const float*)d_in[4];
    const float* gw  = (const float*)d_in[5];
    const float* gb  = (const float*)d_in[6];
    const float* e1w = (const float*)d_in[7];
    const float* e1b = (const float*)d_in[8];
    const float* e2w = (const float*)d_in[9];
    const float* e2b = (const float*)d_in[10];
    const float* smw = (const float*)d_in[11];
    const float* smb = (const float*)d_in[12];
    float* out = (float*)d_out;

    char* ws = (char*)d_ws;
    size_t off = 0;
    auto alloc = [&](size_t bytes) {
        void* p = ws + off;
        off += (bytes + 255) & ~(size_t)255;
        return p;
    };
    _Float16* h16 = (_Float16*)alloc((size_t)NB * D_IN * 2);          // 52.4 MB
    _Float16* wT  = (_Float16*)alloc((size_t)NE * D_H * D_IN * 2);    // 4.1 MB
    _Float16* e2T = (_Float16*)alloc((size_t)NE * D_H * D_H * 2);     // 0.16 MB
    float* wfull  = (float*)alloc((size_t)NB * NE * 4);               // 0.16 MB
    float* logits = (float*)alloc((size_t)NB * 10 * 4);               // 0.33 MB
    float* gwC    = (float*)alloc((size_t)NE * D_IN * 4);             // 64 KB
    _Float16* wpk = (_Float16*)alloc((size_t)11520 * 2);              // 23 KB packed weights
    int* cnt      = (int*)alloc(NE * 4);
    int* lists    = (int*)alloc((size_t)NE * NB * 4);                 // 160 KB

    hipMemsetAsync(logits, 0, (size_t)NB * 10 * 4, stream);
    k_prep<<<dim3(85), 256, 0, stream>>>(gw, c2w, c1w, gwC, wpk, cnt);
    k_feat<<<dim3(520 + NB), 256, 0, stream>>>(x, c1b, c2b, gwC, gb, wpk,
                                               e1w, wT, e2w, e2T, h16, wfull,
                                               cnt, lists);
    k_e1e2<<<dim3(128 * NE), 256, 0, stream>>>(h16, wT, e2T, e1b, e2b, smw,
                                               wfull, cnt, lists, logits);
    k_smax<<<dim3(NB / 256), 256, 0, stream>>>(logits, smb, out);
}

// Round 10
// 251.678 us; speedup vs baseline: 1.7763x; 1.7763x over previous
//
#include <hip/hip_runtime.h>
#include <hip/hip_bf16.h>
#include <hip/hip_fp16.h>

#define NB 8192
#define D_IN 3200
#define D_H 128
#define NE 5

typedef _Float16 f16x8 __attribute__((ext_vector_type(8)));
typedef _Float16 f16x4 __attribute__((ext_vector_type(4)));
typedef float f32x4 __attribute__((ext_vector_type(4)));

// async global->LDS, 16B per lane; global addr may be per-lane, LDS base wave-uniform
__device__ __forceinline__ void gload16(const _Float16* g, _Float16* l) {
    __builtin_amdgcn_global_load_lds(
        (const __attribute__((address_space(1))) void*)g,
        (__attribute__((address_space(3))) void*)l, 16, 0, 0);
}

__device__ __forceinline__ unsigned pack_hl(float v) {
    _Float16 vh = (_Float16)v;
    _Float16 vl = (_Float16)(v - (float)vh);
    unsigned short uh, ul;
    __builtin_memcpy(&uh, &vh, 2);
    __builtin_memcpy(&ul, &vl, 2);
    return (unsigned)uh | ((unsigned)ul << 16);
}

// ---------------- kernel 0: prep — ROUND-4 EXACT (frozen)
// wpk: [0,5120) b2h | [5120,10240) b2l | [10240,10880) b1h | [10880,11520) b1l
__global__ __launch_bounds__(256) void k_prep(const float* __restrict__ gw,
                                              const float* __restrict__ c2w,
                                              const float* __restrict__ c1w,
                                              float* __restrict__ gwC,
                                              _Float16* __restrict__ wpk,
                                              int* __restrict__ cnt) {
    int i = blockIdx.x * 256 + threadIdx.x;
    if (i < 16000) {
        int e = i / 3200, rem = i - e * 3200;
        int o = rem >> 5, co = rem & 31;
        gwC[i] = gw[(co * 100 + o) * 5 + e];
    } else if (i < 21120) {
        int j = i - 16000;                 // b2 pack, j in [0,5120)
        int co = j / 160, k = j - co * 160;
        int s = k >> 4, ci = k & 15;
        float v = (s == 9) ? 0.f : c2w[(co * 16 + ci) * 9 + s];
        _Float16 vh = (_Float16)v;
        wpk[j] = vh;
        wpk[5120 + j] = (_Float16)(v - (float)vh);
    } else if (i < 21760) {
        int j = i - 21120;                 // b1 pack, j in [0,640) = [c][k<40]
        int c = (j * 1639) >> 16;          // j/40
        int k = j - c * 40;
        float v = (k < 25) ? c1w[c * 25 + k] : 0.f;
        _Float16 vh = (_Float16)v;
        wpk[10240 + j] = vh;
        wpk[10880 + j] = (_Float16)(v - (float)vh);
    }
    if (blockIdx.x == 0 && threadIdx.x < NE) cnt[threadIdx.x] = 0;
}

// ---------------- kernel 1: blocks 0-519 = wT/e2T transpose prep; blocks 520+ = conv path.
// ROUND-4 EXACT (measured ~107us): conv1 on MFMA, hoisted repack, gwC scalar gate.
// Round-9 lesson: do NOT fuse compaction atomics into the t==0 tail — same-line
// device atomics gate block retirement (107 -> 302us). Keep k_compact separate.
#define PCL_S 24
__global__ __launch_bounds__(256, 4) void k_feat(
    const float* __restrict__ x, const float* __restrict__ c1b,
    const float* __restrict__ c2b,
    const float* __restrict__ gwC, const float* __restrict__ gb,
    const _Float16* __restrict__ wpk,
    const float* __restrict__ e1w, _Float16* __restrict__ wT,
    const float* __restrict__ e2w, _Float16* __restrict__ e2T,
    _Float16* __restrict__ h16, float* __restrict__ wfull)
{
    __shared__ union {
        struct {
            __align__(16) _Float16 b2h[5120];   // contiguous staging run start
            __align__(16) _Float16 b2l[5120];
            __align__(16) _Float16 b1h[640];
            __align__(16) _Float16 b1l[640];
            __align__(16) unsigned xs_hl[784];
            __align__(16) _Float16 pclh[144 * PCL_S];
            __align__(16) _Float16 pcll[144 * PCL_S];
            float red[32];
        } f;
        float tile[64 * 65];   // prep transpose scratch (16.6 KB, overlaid)
    } S;
    int bid = blockIdx.x;
    int t = threadIdx.x;

    if (bid < 520) {               // ---- prep path
        if (bid < 500) {           // e1_w [5][3200][128] -> f16 T [5][128][3200]
            int e = bid / 100, rem = bid - e * 100;
            int k0 = (rem >> 1) * 64, n0 = (rem & 1) * 64;
            const float* src = e1w + (size_t)e * D_IN * D_H;
            _Float16* dst = wT + (size_t)e * D_H * D_IN;
            for (int i = 0; i < 16; ++i) {
                int idx = t + i * 256;
                int kr = idx >> 6, nc = idx & 63;
                S.tile[kr * 65 + nc] = src[(size_t)(k0 + kr) * D_H + n0 + nc];
            }
            __syncthreads();
            for (int i = 0; i < 16; ++i) {
                int idx = t + i * 256;
                int nr = idx >> 6, kc = idx & 63;
                dst[(size_t)(n0 + nr) * D_IN + k0 + kc] = (_Float16)S.tile[kc * 65 + nr];
            }
        } else {                   // e2_w [5][128][128] -> f16 T (n,k)
            int idx2 = bid - 500;
            int e = idx2 >> 2, rem = idx2 & 3;
            int k0 = (rem >> 1) * 64, n0 = (rem & 1) * 64;
            const float* src = e2w + (size_t)e * D_H * D_H;
            _Float16* dst = e2T + (size_t)e * D_H * D_H;
            for (int i = 0; i < 16; ++i) {
                int idx = t + i * 256;
                int kr = idx >> 6, nc = idx & 63;
                S.tile[kr * 65 + nc] = src[(size_t)(k0 + kr) * D_H + n0 + nc];
            }
            __syncthreads();
            for (int i = 0; i < 16; ++i) {
                int idx = t + i * 256;
                int nr = idx >> 6, kc = idx & 63;
                dst[(size_t)(n0 + nr) * D_H + k0 + kc] = (_Float16)S.tile[kc * 65 + nr];
            }
        }
        return;
    }

    int b = bid - 520;             // ---- conv path
    int lane = t & 63, wv = t >> 6;
    int quad = lane >> 4, l16 = lane & 15;

    // weight staging: 23040 B = 1440 x 16B chunks, async DMA, no VALU repack
    {
        _Float16* ldst = S.f.b2h;
        #pragma unroll
        for (int it = 0; it < 6; ++it) {
            int ci = t + it * 256;
            if (ci < 1440)
                gload16(wpk + ci * 8, ldst + (it * 256 + wv * 64) * 8);
        }
    }
    // x -> packed hi/lo f16 words
    for (int i = t; i < 784; i += 256)
        S.f.xs_hl[i] = pack_hl(x[(size_t)b * 784 + i]);
    __syncthreads();

    // ---- conv1 MFMA + fused 2x2 maxpool
    {
        f16x8 b1hf = *(const f16x8*)&S.f.b1h[l16 * 40 + quad * 8];
        f16x8 b1lf = *(const f16x8*)&S.f.b1l[l16 * 40 + quad * 8];
        float bias1 = c1b[l16];
        int offw[8];
        #pragma unroll
        for (int j = 0; j < 8; ++j) {
            int k = quad * 8 + j; if (k > 24) k = 24;     // B is zero for k>=25
            int uu = (k * 205) >> 10;                     // k/5
            offw[j] = k + 23 * uu;                        // u*28+v
        }
        int s_ = l16 & 3, qof = l16 >> 2;
        int dy = s_ >> 1, dx = s_ & 1;
        for (int T = wv * 9; T < wv * 9 + 9; ++T) {
            int q = T * 4 + qof;                          // A row's pooled pixel
            int qy = (q * 683) >> 13, qx = q - qy * 12;   // q/12, q%12
            int base = (2 * qy + dy) * 28 + 2 * qx + dx;
            unsigned w[8];
            #pragma unroll
            for (int j = 0; j < 8; ++j) w[j] = S.f.xs_hl[base + offw[j]];
            union { f16x8 v; unsigned u[4]; } ah, al;
            #pragma unroll
            for (int jj = 0; jj < 4; ++jj) {
                ah.u[jj] = __builtin_amdgcn_perm(w[2 * jj + 1], w[2 * jj], 0x05040100u);
                al.u[jj] = __builtin_amdgcn_perm(w[2 * jj + 1], w[2 * jj], 0x07060302u);
            }
            f32x4 a1 = (f32x4){0.f, 0.f, 0.f, 0.f};
            a1 = __builtin_amdgcn_mfma_f32_16x16x32_f16(ah.v, b1hf, a1, 0, 0, 0);
            a1 = __builtin_amdgcn_mfma_f32_16x16x32_f16(ah.v, b1lf, a1, 0, 0, 0);
            a1 = __builtin_amdgcn_mfma_f32_16x16x32_f16(al.v, b1hf, a1, 0, 0, 0);
            // lane holds the 4 pool sources of pooled pixel pos = T*4+quad, channel l16
            float pv = fmaxf(fmaxf(a1[0], a1[1]), fmaxf(a1[2], a1[3]));
            pv = fmaxf(pv + bias1, 0.f);
            int pos = T * 4 + quad;
            _Float16 vh = (_Float16)pv;
            S.f.pclh[pos * PCL_S + l16] = vh;
            S.f.pcll[pos * PCL_S + l16] = (_Float16)(pv - (float)vh);
        }
    }
    __syncthreads();

    // conv2 MFMA: wave fixed nt (B frags in regs), mt strided  (proven structure, frozen)
    float part[5] = {0, 0, 0, 0, 0};
    int quadh = quad >> 1, quadl = quad & 1;
    const int offA[5] = {0, 2, 13, 24, 26};
    const int offB[5] = {1, 12, 14, 25, 0};
    {
        int nt = wv & 1;
        int co = nt * 16 + l16;
        f16x8 bh[5], bl[5];
        #pragma unroll
        for (int kc = 0; kc < 5; ++kc) {
            bh[kc] = *(const f16x8*)&S.f.b2h[co * 160 + kc * 32 + quad * 8];
            bl[kc] = *(const f16x8*)&S.f.b2l[co * 160 + kc * 32 + quad * 8];
        }
        float bco = c2b[co];
        for (int mt = wv >> 1; mt < 7; mt += 2) {
            int o_a = mt * 16 + l16;
            int o_cl = o_a < 100 ? o_a : 99;
            int pb = (o_cl / 10) * 12 + (o_cl % 10);
            f32x4 acc = (f32x4){0.f, 0.f, 0.f, 0.f};
            #pragma unroll
            for (int kc = 0; kc < 5; ++kc) {
                int off = quadh ? offB[kc] : offA[kc];
                f16x8 ah = *(const f16x8*)&S.f.pclh[(pb + off) * PCL_S + quadl * 8];
                f16x8 al = *(const f16x8*)&S.f.pcll[(pb + off) * PCL_S + quadl * 8];
                acc = __builtin_amdgcn_mfma_f32_16x16x32_f16(ah, bh[kc], acc, 0, 0, 0);
                acc = __builtin_amdgcn_mfma_f32_16x16x32_f16(ah, bl[kc], acc, 0, 0, 0);
                acc = __builtin_amdgcn_mfma_f32_16x16x32_f16(al, bh[kc], acc, 0, 0, 0);
            }
            if (mt < 6 || quad == 0) {
                int o0 = mt * 16 + quad * 4;
                f16x4 st;
                #pragma unroll
                for (int r = 0; r < 4; ++r) {
                    float hv = fmaxf(acc[r] + bco, 0.f);
                    st[r] = (_Float16)hv;
                    #pragma unroll
                    for (int e = 0; e < 5; ++e)
                        part[e] += hv * gwC[e * 3200 + (o0 + r) * 32 + co];
                }
                *(f16x4*)&h16[(size_t)b * D_IN + co * 100 + o0] = st;
            }
        }
    }

    // gate reduce: softmax, top-3 renormalized
    #pragma unroll
    for (int e = 0; e < 5; ++e) {
        float v = part[e];
        for (int off = 32; off > 0; off >>= 1) v += __shfl_down(v, off, 64);
        if (lane == 0) S.f.red[wv * 8 + e] = v;
    }
    __syncthreads();
    if (t == 0) {
        float lg[5], p[5];
        float mx = -1e30f;
        for (int e = 0; e < 5; ++e) {
            lg[e] = S.f.red[e] + S.f.red[8 + e] + S.f.red[16 + e] + S.f.red[24 + e] + gb[e];
            mx = fmaxf(mx, lg[e]);
        }
        float sum = 0.f;
        for (int e = 0; e < 5; ++e) { p[e] = expf(lg[e] - mx); sum += p[e]; }
        for (int e = 0; e < 5; ++e) p[e] /= sum;
        bool used[5] = {false, false, false, false, false};
        float out5[5] = {0, 0, 0, 0, 0};
        int ti[3]; float tv[3]; float tsum = 0.f;
        for (int jj = 0; jj < 3; ++jj) {
            int best = 0; float bv = -1.f;
            for (int e = 0; e < 5; ++e)
                if (!used[e] && p[e] > bv) { bv = p[e]; best = e; }
            used[best] = true; ti[jj] = best; tv[jj] = bv; tsum += bv;
        }
        for (int jj = 0; jj < 3; ++jj) out5[ti[jj]] = tv[jj] / tsum;
        for (int e = 0; e < 5; ++e) wfull[b * 5 + e] = out5[e];
    }
}

// ---------------- kernel 1b: token compaction — wave-aggregated (640 atomics total)
__global__ __launch_bounds__(256) void k_compact(
    const float* __restrict__ wfull, int* __restrict__ cnt, int* __restrict__ lists)
{
    int tok = blockIdx.x * 256 + threadIdx.x;
    int lane = threadIdx.x & 63;
    float w[5];
    #pragma unroll
    for (int e = 0; e < 5; ++e) w[e] = wfull[(size_t)tok * 5 + e];
    #pragma unroll
    for (int e = 0; e < 5; ++e) {
        bool sel = w[e] > 0.f;
        unsigned long long mask = __ballot(sel);
        int leader = __ffsll((long long)mask) - 1;
        int base = 0;
        if (lane == leader) base = atomicAdd(&cnt[e], __popcll(mask));
        base = __shfl(base, leader, 64);
        if (sel) {
            int pos = base + __popcll(mask & ((1ull << lane) - 1ull));
            lists[e * NB + pos] = tok;
        }
    }
}

// ---------------- kernel 2: experts on compacted lists, 64-row M-tiles — ROUND-7 EXACT
// (measured best: total 251.9us). 3-deep staging ring, steady-state vmcnt(12) (2 stages
// in flight, never drained). Phase-2 B frags read e2T DIRECT from global (L2-hot per
// expert). h1s/smwT overlay dead staging. 74KB -> 2 blocks/CU.
#define H1S 136
union __align__(16) SLds {
    struct { _Float16 d[12288]; } p[3];               // 3 x 24KB staging
    struct {
        __align__(16) _Float16 h1s[64 * H1S];         // 17.4 KB activations (phase 2/3)
        __align__(16) _Float16 smwT[2048];            // 4 KB head weights^T (phase 3)
    } q;
};

__global__ __launch_bounds__(256, 2) void k_e1e2(
    const _Float16* __restrict__ h16, const _Float16* __restrict__ wT,
    const _Float16* __restrict__ e2T,
    const float* __restrict__ e1b, const float* __restrict__ e2b,
    const float* __restrict__ smw,
    const float* __restrict__ wfull, const int* __restrict__ cnt,
    const int* __restrict__ lists, float* __restrict__ logits)
{
    __shared__ SLds u;
    __shared__ float wfl[64];
    __shared__ int rows[64];
    int bid = blockIdx.x;
    int e = bid >> 7;            // expert-major: one B matrix hot per L2 at a time
    int mt = bid & 127;
    int cnt_e = cnt[e];
    int m0 = mt * 64;
    if (m0 >= cnt_e) return;     // inactive tile, uniform exit
    int t = threadIdx.x;
    int lane = t & 63, wv = t >> 6;
    int waveM = wv >> 1, waveN = wv & 1;
    int quad = lane >> 4, l16 = lane & 15;
    if (t < 64) {
        int r = m0 + t;
        int row = (r < cnt_e) ? lists[e * NB + r] : lists[e * NB];  // dup row for tail
        rows[t] = row;
        wfl[t] = (r < cnt_e) ? wfull[(size_t)row * 5 + e] : 0.f;    // tail w=0
    }
    __syncthreads();

    const _Float16* bbase = wT + (size_t)e * (D_H * D_IN);
    int srow = t >> 2;
    int scol = (t & 3) * 8;
    const _Float16* aptr = h16 + (size_t)rows[srow] * D_IN + scol;
    const _Float16* bptr0 = bbase + (size_t)srow * D_IN + scol;
    const _Float16* bptr1 = bbase + (size_t)(64 + srow) * D_IN + scol;
    f32x4 acc[2][4];
    #pragma unroll
    for (int i = 0; i < 2; ++i)
        #pragma unroll
        for (int j = 0; j < 4; ++j) acc[i][j] = (f32x4){0.f, 0.f, 0.f, 0.f};

    _Float16* bcur = (_Float16*)&u.p[0];
    _Float16* bnxt = (_Float16*)&u.p[1];
    _Float16* bnx2 = (_Float16*)&u.p[2];
    // buffer layout: [0]=As0(k lo half), [2048]=As1(k hi), [4096]=Bs0, [8192]=Bs1
    #define STAGE(base, kk)                                           \
        do {                                                          \
            gload16(aptr  + (kk),        (base) + 0    + wv * 512);   \
            gload16(aptr  + (kk) + 32,   (base) + 2048 + wv * 512);   \
            gload16(bptr0 + (kk),        (base) + 4096 + wv * 512);   \
            gload16(bptr0 + (kk) + 32,   (base) + 8192 + wv * 512);   \
            gload16(bptr1 + (kk),        (base) + 4096 + 2048 + wv * 512); \
            gload16(bptr1 + (kk) + 32,   (base) + 8192 + 2048 + wv * 512); \
        } while (0)

    STAGE(bcur, 0);                               // prologue: steps 0,1 in flight
    STAGE(bnxt, 64);
    const int NT = D_IN / 64;                     // 50
    for (int it = 0; it < NT; ++it) {
        if (it + 2 < NT) {
            STAGE(bnx2, (it + 2) * 64);           // keep 2 stages in flight
            asm volatile("s_waitcnt vmcnt(12)" ::: "memory");  // oldest stage (it) done
        } else if (it + 1 < NT) {
            asm volatile("s_waitcnt vmcnt(6)" ::: "memory");
        } else {
            asm volatile("s_waitcnt vmcnt(0)" ::: "memory");
        }
        __builtin_amdgcn_s_barrier();             // all waves: bcur fully populated
        __builtin_amdgcn_sched_barrier(0);
        #pragma unroll
        for (int ch = 0; ch < 2; ++ch) {
            const _Float16* Ab = bcur + (ch ? 2048 : 0);
            const _Float16* Bb = bcur + 4096 + (ch ? 4096 : 0);
            f16x8 af[2], bf[4];
            #pragma unroll
            for (int ms = 0; ms < 2; ++ms)
                af[ms] = *(const f16x8*)&Ab[(waveM * 32 + ms * 16 + l16) * 32 + quad * 8];
            #pragma unroll
            for (int ns = 0; ns < 4; ++ns)
                bf[ns] = *(const f16x8*)&Bb[(waveN * 64 + ns * 16 + l16) * 32 + quad * 8];
            #pragma unroll
            for (int ms = 0; ms < 2; ++ms)
                #pragma unroll
                for (int ns = 0; ns < 4; ++ns)
                    acc[ms][ns] = __builtin_amdgcn_mfma_f32_16x16x32_f16(af[ms], bf[ns], acc[ms][ns], 0, 0, 0);
        }
        __builtin_amdgcn_s_barrier();             // all reads retired -> bcur reusable
        _Float16* t0 = bcur; bcur = bnxt; bnxt = bnx2; bnx2 = t0;
    }
    #undef STAGE

    // h1 = tanh(acc + b1) -> h1s (staging dead; q overlays p)
    #pragma unroll
    for (int ms = 0; ms < 2; ++ms) {
        int rbase = waveM * 32 + ms * 16 + quad * 4;
        #pragma unroll
        for (int ns = 0; ns < 4; ++ns) {
            int n = waveN * 64 + ns * 16 + l16;
            float bias = e1b[e * D_H + n];
            #pragma unroll
            for (int r = 0; r < 4; ++r)
                u.q.h1s[(rbase + r) * H1S + n] = (_Float16)tanhf(acc[ms][ns][r] + bias);
        }
    }
    __syncthreads();   // h1s visible

    // phase 2: h1 @ e2^T, B frags direct from global e2T (L2-hot, shared per expert)
    const _Float16* e2g = e2T + (size_t)e * (D_H * D_H);
    f32x4 acc2[2][4];
    #pragma unroll
    for (int i = 0; i < 2; ++i)
        #pragma unroll
        for (int j = 0; j < 4; ++j) acc2[i][j] = (f32x4){0.f, 0.f, 0.f, 0.f};
    #pragma unroll
    for (int kc = 0; kc < 4; ++kc) {
        f16x8 a2[2], b2[4];
        #pragma unroll
        for (int ms = 0; ms < 2; ++ms)
            a2[ms] = *(const f16x8*)&u.q.h1s[(waveM * 32 + ms * 16 + l16) * H1S + kc * 32 + quad * 8];
        #pragma unroll
        for (int ns = 0; ns < 4; ++ns)
            b2[ns] = *(const f16x8*)&e2g[(size_t)(waveN * 64 + ns * 16 + l16) * D_H + kc * 32 + quad * 8];
        #pragma unroll
        for (int ms = 0; ms < 2; ++ms)
            #pragma unroll
            for (int ns = 0; ns < 4; ++ns)
                acc2[ms][ns] = __builtin_amdgcn_mfma_f32_16x16x32_f16(a2[ms], b2[ns], acc2[ms][ns], 0, 0, 0);
    }
    __syncthreads();   // all h1s reads done -> safe to overwrite with wh2

    // stage smw^T [16(n, zero-padded)][128(k)] f16; wh2 = w*tanh(acc2+b2) -> h1s
    _Float16* smwT = u.q.smwT;
    for (int i = t; i < 2048; i += 256) {
        int n = i >> 7, k = i & 127;
        smwT[i] = (_Float16)(n < 10 ? smw[k * 10 + n] : 0.f);
    }
    #pragma unroll
    for (int ms = 0; ms < 2; ++ms) {
        int rbase = waveM * 32 + ms * 16 + quad * 4;
        #pragma unroll
        for (int ns = 0; ns < 4; ++ns) {
            int n = waveN * 64 + ns * 16 + l16;
            float bias = e2b[e * D_H + n];
            #pragma unroll
            for (int r = 0; r < 4; ++r) {
                int lrow = rbase + r;
                u.q.h1s[lrow * H1S + n] = (_Float16)(wfl[lrow] * tanhf(acc2[ms][ns][r] + bias));
            }
        }
    }
    __syncthreads();

    // MFMA head: per wave one 16-row m-tile: wh2[16x128] @ smw^T[16x128] -> atomic logits
    {
        f32x4 acc3 = (f32x4){0.f, 0.f, 0.f, 0.f};
        #pragma unroll
        for (int kc = 0; kc < 4; ++kc) {
            f16x8 a3 = *(const f16x8*)&u.q.h1s[(wv * 16 + l16) * H1S + kc * 32 + quad * 8];
            f16x8 b3 = *(const f16x8*)&smwT[l16 * 128 + kc * 32 + quad * 8];
            acc3 = __builtin_amdgcn_mfma_f32_16x16x32_f16(a3, b3, acc3, 0, 0, 0);
        }
        if (l16 < 10) {     // D: row = quad*4+r, col = l16
            #pragma unroll
            for (int r = 0; r < 4; ++r) {
                int row = wv * 16 + quad * 4 + r;
                unsafeAtomicAdd(&logits[(size_t)rows[row] * 10 + l16], acc3[r]);
            }
        }
    }
}

// ---------------- kernel 3: softmax over logits (+smb) -> out
__global__ __launch_bounds__(256) void k_smax(
    const float* __restrict__ logits, const float* __restrict__ smb,
    float* __restrict__ out)
{
    int r = blockIdx.x * 256 + threadIdx.x;
    float lg[10];
    float mx = -1e30f;
    #pragma unroll
    for (int c = 0; c < 10; ++c) {
        lg[c] = logits[(size_t)r * 10 + c] + smb[c];
        mx = fmaxf(mx, lg[c]);
    }
    float s = 0.f;
    #pragma unroll
    for (int c = 0; c < 10; ++c) { lg[c] = expf(lg[c] - mx); s += lg[c]; }
    float inv = 1.f / s;
    #pragma unroll
    for (int c = 0; c < 10; ++c) out[(size_t)r * 10 + c] = lg[c] * inv;
}

extern "C" void kernel_launch(void* const* d_in, const int* in_sizes, int n_in,
                              void* d_out, int out_size, void* d_ws, size_t ws_size,
                              hipStream_t stream)
{
    const float* x   = (const float*)d_in[0];
    const float* c1w = (const float*)d_in[1];
    const float* c1b = (const float*)d_in[2];
    const float* c2w = (const float*)d_in[3];
    const float* c2b = (const float*)d_in[4];
    const float* gw  = (const float*)d_in[5];
    const float* gb  = (const float*)d_in[6];
    const float* e1w = (const float*)d_in[7];
    const float* e1b = (const float*)d_in[8];
    const float* e2w = (const float*)d_in[9];
    const float* e2b = (const float*)d_in[10];
    const float* smw = (const float*)d_in[11];
    const float* smb = (const float*)d_in[12];
    float* out = (float*)d_out;

    char* ws = (char*)d_ws;
    size_t off = 0;
    auto alloc = [&](size_t bytes) {
        void* p = ws + off;
        off += (bytes + 255) & ~(size_t)255;
        return p;
    };
    _Float16* h16 = (_Float16*)alloc((size_t)NB * D_IN * 2);          // 52.4 MB
    _Float16* wT  = (_Float16*)alloc((size_t)NE * D_H * D_IN * 2);    // 4.1 MB
    _Float16* e2T = (_Float16*)alloc((size_t)NE * D_H * D_H * 2);     // 0.16 MB
    float* wfull  = (float*)alloc((size_t)NB * NE * 4);               // 0.16 MB
    float* logits = (float*)alloc((size_t)NB * 10 * 4);               // 0.33 MB
    float* gwC    = (float*)alloc((size_t)NE * D_IN * 4);             // 64 KB
    _Float16* wpk = (_Float16*)alloc((size_t)11520 * 2);              // 23 KB packed weights
    int* cnt      = (int*)alloc(NE * 4);
    int* lists    = (int*)alloc((size_t)NE * NB * 4);                 // 160 KB

    hipMemsetAsync(logits, 0, (size_t)NB * 10 * 4, stream);
    k_prep<<<dim3(85), 256, 0, stream>>>(gw, c2w, c1w, gwC, wpk, cnt);
    k_feat<<<dim3(520 + NB), 256, 0, stream>>>(x, c1b, c2b, gwC, gb, wpk,
                                               e1w, wT, e2w, e2T, h16, wfull);
    k_compact<<<dim3(NB / 256), 256, 0, stream>>>(wfull, cnt, lists);
    k_e1e2<<<dim3(128 * NE), 256, 0, stream>>>(h16, wT, e2T, e1b, e2b, smw,
                                               wfull, cnt, lists, logits);
    k_smax<<<dim3(NB / 256), 256, 0, stream>>>(logits, smb, out);
}